// Round 9
// baseline (1265.804 us; speedup 1.0000x reference)
//
#include <hip/hip_runtime.h>
#include <cmath>

#define NPTS 256
#define TOTPTS 32768
#define KNB 16

// ---------------- workspace layout (float-element offsets) ----------------
// UZ region doubles as the per-layer fp64 neg-dist matrix (64 MiB) during knn.
// YMAX region's head doubles as per-point fp64 sq norms (256 KiB) during knn.
static const size_t OFF_HA   = 0;
static const size_t OFF_HB   = 4194304;
static const size_t OFF_UZ   = 6291456;
static const size_t OFF_YMAX = 23068672;
static const size_t OFF_YMIN = 31457280;
static const size_t OFF_IDX  = 39845888;
static const size_t OFF_VT   = 40370176;
static const size_t OFF_SUMS = 40458240;   // byte offset 161,832,960 (8-aligned)

__device__ __forceinline__ float gelu_erf(float v) {
  return 0.5f * v * (1.0f + erff(v * 0.70710678118654752f));
}

// ---------------- prep: transpose x -> h0, build Vt, zero stats ----------------
__global__ __launch_bounds__(256) void prep_kernel(
    const float* __restrict__ x, float* __restrict__ h0,
    const float* __restrict__ W1, const float* __restrict__ W2, const float* __restrict__ W3,
    const float* __restrict__ W4, const float* __restrict__ W5,
    float* __restrict__ Vt, double* __restrict__ sums) {
  const int stride = gridDim.x * blockDim.x;
  const int tid0 = blockIdx.x * blockDim.x + threadIdx.x;
  // x: (4,6,32,256) -> h0: (128 clouds, 256 pts, 6 ch)
  for (int id = tid0; id < 196608; id += stride) {
    int ch = id % 6;
    int r  = id / 6;            // r = cloud*256 + s
    int s  = r & 255;
    int p  = (r >> 8) & 31;
    int bs = r >> 13;
    h0[id] = x[(((size_t)(bs * 6 + ch) * 32 + p) << 8) + s];
  }
  // Vt[l]: (Cin x 2O), Vt[c*2O + j] = W[j<O ? j*2Cin+c : (j-O)*2Cin+Cin+c]
  for (int id = tid0; id < 87232; id += stride) {
    const float* W; int K, N2, base;
    if (id < 192)        { W = W1; K = 6;   N2 = 32;  base = 0; }
    else if (id < 1216)  { W = W2; K = 16;  N2 = 64;  base = 192; }
    else if (id < 5312)  { W = W3; K = 32;  N2 = 128; base = 1216; }
    else if (id < 21696) { W = W4; K = 64;  N2 = 256; base = 5312; }
    else                 { W = W5; K = 128; N2 = 512; base = 21696; }
    int e = id - base;
    int c = e / N2;
    int j = e - c * N2;
    int O = N2 >> 1;
    Vt[id] = (j < O) ? W[j * 2 * K + c] : W[(j - O) * 2 * K + K + c];
  }
  for (int id = tid0; id < 992; id += stride) sums[id] = 0.0;
}

// ---------------- sq: per-point fp64 squared norm ----------------
template<int C>
__global__ __launch_bounds__(256) void sq_kernel(const float* __restrict__ h,
                                                 double* __restrict__ sqd) {
  const int n = blockIdx.x * 256 + threadIdx.x;
  const float* p = h + (size_t)n * C;
  double q0 = 0.0, q1 = 0.0;
  #pragma unroll
  for (int c = 0; c + 1 < C; c += 2) {
    q0 = fma((double)p[c],   (double)p[c],   q0);
    q1 = fma((double)p[c+1], (double)p[c+1], q1);
  }
  #pragma unroll
  for (int c = C & ~1; c < C; ++c) q0 = fma((double)p[c], (double)p[c], q0);
  sqd[n] = q0 + q1;
}

// ---------------- dist: fp64 neg-dist matrix, register-tiled GEMM ----------------
// nd[cloud][i][j] = 2*<h_i,h_j> - sq_i - sq_j  (exact ranking key, fp64)
// grid: 128 clouds x 16 tiles (4x4 grid of 64x64 tiles), 256 threads
template<int K>
__global__ __launch_bounds__(256) void dist_kernel(const float* __restrict__ h,
                                                   const double* __restrict__ sqd,
                                                   double* __restrict__ nd) {
  constexpr int KC = (K < 32) ? K : 32;
  __shared__ __align__(16) float As[KC * 68];   // [k][i]
  __shared__ __align__(16) float Bs[KC * 68];   // [k][j]
  const int cloud = blockIdx.x >> 4;
  const int tile  = blockIdx.x & 15;
  const int i0 = (tile >> 2) * 64;
  const int j0 = (tile & 3) * 64;
  const float* hb = h + (size_t)cloud * NPTS * K;
  const int tid = threadIdx.x;
  const int mm = (tid & 15) * 4;
  const int jj = (tid >> 4) * 4;
  double acc[4][4] = {{0.0}};
  for (int k0 = 0; k0 < K; k0 += KC) {
    for (int e = tid; e < 64 * KC; e += 256) {
      int am = e / KC, ac = e - am * KC;
      As[ac * 68 + am] = hb[(size_t)(i0 + am) * K + k0 + ac];
    }
    for (int e = tid; e < 64 * KC; e += 256) {
      int bm = e / KC, bc = e - bm * KC;
      Bs[bc * 68 + bm] = hb[(size_t)(j0 + bm) * K + k0 + bc];
    }
    __syncthreads();
    #pragma unroll
    for (int c = 0; c < KC; ++c) {
      float4 av = *(const float4*)(As + c * 68 + mm);
      float4 bv = *(const float4*)(Bs + c * 68 + jj);
      double a0 = (double)av.x, a1 = (double)av.y, a2 = (double)av.z, a3 = (double)av.w;
      double b0 = (double)bv.x, b1 = (double)bv.y, b2 = (double)bv.z, b3 = (double)bv.w;
      acc[0][0] = fma(a0, b0, acc[0][0]);
      acc[0][1] = fma(a0, b1, acc[0][1]);
      acc[0][2] = fma(a0, b2, acc[0][2]);
      acc[0][3] = fma(a0, b3, acc[0][3]);
      acc[1][0] = fma(a1, b0, acc[1][0]);
      acc[1][1] = fma(a1, b1, acc[1][1]);
      acc[1][2] = fma(a1, b2, acc[1][2]);
      acc[1][3] = fma(a1, b3, acc[1][3]);
      acc[2][0] = fma(a2, b0, acc[2][0]);
      acc[2][1] = fma(a2, b1, acc[2][1]);
      acc[2][2] = fma(a2, b2, acc[2][2]);
      acc[2][3] = fma(a2, b3, acc[2][3]);
      acc[3][0] = fma(a3, b0, acc[3][0]);
      acc[3][1] = fma(a3, b1, acc[3][1]);
      acc[3][2] = fma(a3, b2, acc[3][2]);
      acc[3][3] = fma(a3, b3, acc[3][3]);
    }
    __syncthreads();
  }
  double sqi[4], sqj[4];
  #pragma unroll
  for (int r = 0; r < 4; ++r) sqi[r] = sqd[cloud * NPTS + i0 + mm + r];
  #pragma unroll
  for (int s = 0; s < 4; ++s) sqj[s] = sqd[cloud * NPTS + j0 + jj + s];
  double* orow = nd + (size_t)cloud * NPTS * NPTS;
  #pragma unroll
  for (int r = 0; r < 4; ++r) {
    double v0 = 2.0 * acc[r][0] - sqi[r] - sqj[0];
    double v1 = 2.0 * acc[r][1] - sqi[r] - sqj[1];
    double v2 = 2.0 * acc[r][2] - sqi[r] - sqj[2];
    double v3 = 2.0 * acc[r][3] - sqi[r] - sqj[3];
    double* p = orow + (size_t)(i0 + mm + r) * NPTS + j0 + jj;
    *(double2*)(p)     = make_double2(v0, v1);
    *(double2*)(p + 2) = make_double2(v2, v3);
  }
}

// ------- topk: wave-per-row tournament on u64 index-embedded keys.
// nd values are <=0 (fp noise ~1e-13 around 0 on/near the diagonal), so
// value-DESCENDING order == ascending u64 bit order (tiny-positive tier first
// ~= the +-0 ties; among negatives smaller u64 = larger value). Low 8 mantissa
// bits carry the column (perturbation ~2^-44 rel, selection-safe; exact-dup
// ties -> lower col). Only the index SET matters downstream (max over k and
// BN sums are order-invariant). Each round: min-of-4 chain (static scalars,
// no arrays -> no scratch), 6-step shfl_xor u64-min butterfly, winner lane
// clears its slot via 4 static compares. Structure proven in R6.
__global__ __launch_bounds__(256) void topk_tourn_kernel(const double* __restrict__ nd,
                                                         int* __restrict__ idxout) {
  const int row  = (blockIdx.x * 256 + (int)threadIdx.x) >> 6;   // one row per wave
  const int lane = threadIdx.x & 63;
  const double* rp = nd + (size_t)row * NPTS + 4 * lane;
  double2 p0 = *(const double2*)(rp);
  double2 p1 = *(const double2*)(rp + 2);
  const unsigned long long FULL = 0xFFFFFFFFFFFFFFFFull;
  const unsigned c0 = 4u * lane;
  unsigned long long k0 = ((unsigned long long)__double_as_longlong(p0.x) & ~0xFFull) | (c0 + 0u);
  unsigned long long k1 = ((unsigned long long)__double_as_longlong(p0.y) & ~0xFFull) | (c0 + 1u);
  unsigned long long k2 = ((unsigned long long)__double_as_longlong(p1.x) & ~0xFFull) | (c0 + 2u);
  unsigned long long k3 = ((unsigned long long)__double_as_longlong(p1.y) & ~0xFFull) | (c0 + 3u);
  int keep = 0;
  #pragma unroll
  for (int round = 0; round < KNB; ++round) {
    unsigned long long m01 = (k0 < k1) ? k0 : k1;
    unsigned long long m23 = (k2 < k3) ? k2 : k3;
    unsigned long long lm  = (m01 < m23) ? m01 : m23;
    #pragma unroll
    for (int off = 32; off >= 1; off >>= 1) {
      unsigned long long o = __shfl_xor(lm, off);
      lm = (o < lm) ? o : lm;
    }
    // all lanes agree on the winning key; its column is embedded
    const int col = (int)(lm & 0xFFull);
    if ((col >> 2) == lane) {
      if ((col & 3) == 0) k0 = FULL;
      if ((col & 3) == 1) k1 = FULL;
      if ((col & 3) == 2) k2 = FULL;
      if ((col & 3) == 3) k3 = FULL;
    }
    if (lane == round) keep = col;
  }
  if (lane < KNB) {
    const int base = row & ~(NPTS - 1);   // cloud base (global point id space)
    idxout[(size_t)row * KNB + lane] = base + keep;
  }
}

// ---------------- GEMM: UZ(32768 x 2O) = h(32768 x K) * Vt(K x 2O) ----------------
template<int K, int N2>
__global__ __launch_bounds__(256) void gemm_uz_kernel(const float* __restrict__ h,
                                                      const float* __restrict__ Vt,
                                                      float* __restrict__ UZ) {
  constexpr int KC = 32;
  constexpr int NBLK = (N2 + 63) / 64;
  __shared__ __align__(16) float As[KC * 68];   // [k][m]
  __shared__ __align__(16) float Bs[KC * 68];   // [k][j]
  const int m0 = (int)(blockIdx.x / NBLK) * 64;
  const int n0 = (int)(blockIdx.x % NBLK) * 64;
  const int tid = threadIdx.x;
  const int mm = (tid & 15) * 4;
  const int jj = (tid >> 4) * 4;
  float acc[4][4] = {{0.f}};
  for (int k0 = 0; k0 < K; k0 += KC) {
    #pragma unroll
    for (int e = tid; e < 64 * KC; e += 256) {
      int am = e / KC, ac = e - am * KC;
      float v = 0.f;
      if (k0 + ac < K) v = h[(size_t)(m0 + am) * K + k0 + ac];
      As[ac * 68 + am] = v;
    }
    #pragma unroll
    for (int e = tid; e < KC * 64; e += 256) {
      int bj = e & 63, bc = e >> 6;
      float v = 0.f;
      if (k0 + bc < K && n0 + bj < N2) v = Vt[(size_t)(k0 + bc) * N2 + n0 + bj];
      Bs[bc * 68 + bj] = v;
    }
    __syncthreads();
    #pragma unroll
    for (int c = 0; c < KC; ++c) {
      float4 av = *(const float4*)(As + c * 68 + mm);
      float4 bv = *(const float4*)(Bs + c * 68 + jj);
      acc[0][0] = fmaf(av.x, bv.x, acc[0][0]);
      acc[0][1] = fmaf(av.x, bv.y, acc[0][1]);
      acc[0][2] = fmaf(av.x, bv.z, acc[0][2]);
      acc[0][3] = fmaf(av.x, bv.w, acc[0][3]);
      acc[1][0] = fmaf(av.y, bv.x, acc[1][0]);
      acc[1][1] = fmaf(av.y, bv.y, acc[1][1]);
      acc[1][2] = fmaf(av.y, bv.z, acc[1][2]);
      acc[1][3] = fmaf(av.y, bv.w, acc[1][3]);
      acc[2][0] = fmaf(av.z, bv.x, acc[2][0]);
      acc[2][1] = fmaf(av.z, bv.y, acc[2][1]);
      acc[2][2] = fmaf(av.z, bv.z, acc[2][2]);
      acc[2][3] = fmaf(av.z, bv.w, acc[2][3]);
      acc[3][0] = fmaf(av.w, bv.x, acc[3][0]);
      acc[3][1] = fmaf(av.w, bv.y, acc[3][1]);
      acc[3][2] = fmaf(av.w, bv.z, acc[3][2]);
      acc[3][3] = fmaf(av.w, bv.w, acc[3][3]);
    }
    __syncthreads();
  }
  if (n0 + jj < N2) {
    #pragma unroll
    for (int i = 0; i < 4; ++i) {
      float4 v = make_float4(acc[i][0], acc[i][1], acc[i][2], acc[i][3]);
      *(float4*)(UZ + (size_t)(m0 + mm + i) * N2 + n0 + jj) = v;
    }
  }
}

// ------- combine (x4 vectorized): gather u rows as float4, max/min + stats ------
template<int O>
__global__ __launch_bounds__(256) void combine_kernel(const float* __restrict__ UZ,
    const int* __restrict__ idx, const float* __restrict__ bias,
    float* __restrict__ ymax, float* __restrict__ ymin, double* __restrict__ sums) {
  constexpr int TPP = O / 4;            // threads per point
  constexpr int PPI = 256 / TPP;        // points per iteration
  constexpr int PPB = TOTPTS / 256;     // 128 points per block
  constexpr int ITERS = PPB / PPI;
  __shared__ double red[256];
  const int tid = threadIdx.x;
  const int oc  = tid % TPP;            // float4-channel index
  const int sub = tid / TPP;
  const int base = blockIdx.x * PPB;
  const float4* UZ4 = (const float4*)UZ;
  float4* ymx4 = (float4*)ymax;
  float4* ymn4 = (float4*)ymin;
  const float4 b4 = ((const float4*)bias)[oc];
  double a1x = 0.0, a1y = 0.0, a1z = 0.0, a1w = 0.0;
  double a2x = 0.0, a2y = 0.0, a2z = 0.0, a2w = 0.0;
  for (int it = 0; it < ITERS; ++it) {
    int n = base + it * PPI + sub;
    const int* ip = idx + (size_t)n * KNB;
    float4 un = UZ4[(size_t)n * (O / 2) + oc];
    float4 zn = UZ4[(size_t)n * (O / 2) + O / 4 + oc];
    float4 w = make_float4(zn.x - un.x + b4.x, zn.y - un.y + b4.y,
                           zn.z - un.z + b4.z, zn.w - un.w + b4.w);
    float4 mx = make_float4(-INFINITY, -INFINITY, -INFINITY, -INFINITY);
    float4 mn = make_float4(INFINITY, INFINITY, INFINITY, INFINITY);
    float4 s1 = make_float4(0.f, 0.f, 0.f, 0.f);
    float4 s2 = make_float4(0.f, 0.f, 0.f, 0.f);
    #pragma unroll
    for (int kk = 0; kk < KNB; ++kk) {
      int j = ip[kk];
      float4 uv = UZ4[(size_t)j * (O / 2) + oc];
      mx.x = fmaxf(mx.x, uv.x); mx.y = fmaxf(mx.y, uv.y);
      mx.z = fmaxf(mx.z, uv.z); mx.w = fmaxf(mx.w, uv.w);
      mn.x = fminf(mn.x, uv.x); mn.y = fminf(mn.y, uv.y);
      mn.z = fminf(mn.z, uv.z); mn.w = fminf(mn.w, uv.w);
      s1.x += uv.x; s1.y += uv.y; s1.z += uv.z; s1.w += uv.w;
      s2.x = fmaf(uv.x, uv.x, s2.x); s2.y = fmaf(uv.y, uv.y, s2.y);
      s2.z = fmaf(uv.z, uv.z, s2.z); s2.w = fmaf(uv.w, uv.w, s2.w);
    }
    ymx4[(size_t)n * (O / 4) + oc] = make_float4(mx.x + w.x, mx.y + w.y, mx.z + w.z, mx.w + w.w);
    ymn4[(size_t)n * (O / 4) + oc] = make_float4(mn.x + w.x, mn.y + w.y, mn.z + w.z, mn.w + w.w);
    a1x += (double)(s1.x + 16.f * w.x);
    a1y += (double)(s1.y + 16.f * w.y);
    a1z += (double)(s1.z + 16.f * w.z);
    a1w += (double)(s1.w + 16.f * w.w);
    a2x += (double)(s2.x + 2.f * w.x * s1.x + 16.f * (w.x * w.x));
    a2y += (double)(s2.y + 2.f * w.y * s1.y + 16.f * (w.y * w.y));
    a2z += (double)(s2.z + 2.f * w.z * s1.z + 16.f * (w.z * w.z));
    a2w += (double)(s2.w + 2.f * w.w * s1.w + 16.f * (w.w * w.w));
  }
  #define REDUCE_ONE(VAL, CH_OFF)                                        \
    red[tid] = (VAL);                                                    \
    __syncthreads();                                                     \
    if (tid < TPP) {                                                     \
      double t = 0.0;                                                    \
      _Pragma("unroll")                                                  \
      for (int q = 0; q < PPI; ++q) t += red[q * TPP + tid];             \
      atomicAdd(&sums[(CH_OFF) + 4 * tid], t);                           \
    }                                                                    \
    __syncthreads();
  REDUCE_ONE(a1x, 0)
  REDUCE_ONE(a1y, 1)
  REDUCE_ONE(a1z, 2)
  REDUCE_ONE(a1w, 3)
  REDUCE_ONE(a2x, O + 0)
  REDUCE_ONE(a2y, O + 1)
  REDUCE_ONE(a2z, O + 2)
  REDUCE_ONE(a2w, O + 3)
  #undef REDUCE_ONE
}

// ---------------- apply: BN affine + erf-GELU + endpoint max ----------------
template<int O>
__global__ __launch_bounds__(256) void apply_kernel(const float* __restrict__ ymax,
    const float* __restrict__ ymin, const double* __restrict__ sums,
    const float* __restrict__ g, const float* __restrict__ bt, float* __restrict__ hout) {
  const int tid = blockIdx.x * 256 + threadIdx.x;
  const int o = tid & (O - 1);
  double m = sums[o] * (1.0 / 524288.0);
  double v = fma(-m, m, sums[O + o] * (1.0 / 524288.0));
  float A = g[o] / sqrtf((float)v + 1e-5f);
  float Cc = fmaf(-(float)m, A, bt[o]);
  float r1 = gelu_erf(fmaf(A, ymax[tid], Cc));
  float r2 = gelu_erf(fmaf(A, ymin[tid], Cc));
  hout[tid] = fmaxf(r1, r2);
}

// layer-5 apply, transposes (n,o) -> (bs, o, p, s) via LDS tile
__global__ __launch_bounds__(256) void apply_final_kernel(const float* __restrict__ ymax,
    const float* __restrict__ ymin, const double* __restrict__ sums,
    const float* __restrict__ g, const float* __restrict__ bt, float* __restrict__ out) {
  constexpr int O = 256;
  __shared__ float tile[64 * 65];
  const int bo = blockIdx.x & 3;
  const int bn = blockIdx.x >> 2;
  const int n0 = bn * 64, o0 = bo * 64;
  const int lane = threadIdx.x & 63;
  const int grp = threadIdx.x >> 6;
  {
    const int oc = o0 + lane;
    double m = sums[oc] * (1.0 / 524288.0);
    double v = fma(-m, m, sums[O + oc] * (1.0 / 524288.0));
    float A = g[oc] / sqrtf((float)v + 1e-5f);
    float Cc = fmaf(-(float)m, A, bt[oc]);
    #pragma unroll
    for (int q = 0; q < 16; ++q) {
      int r = grp * 16 + q;
      size_t src = (size_t)(n0 + r) * O + oc;
      float r1 = gelu_erf(fmaf(A, ymax[src], Cc));
      float r2 = gelu_erf(fmaf(A, ymin[src], Cc));
      tile[r * 65 + lane] = fmaxf(r1, r2);
    }
  }
  __syncthreads();
  const int s0 = n0 & 255;
  const int p  = (n0 >> 8) & 31;
  const int bs = n0 >> 13;
  size_t basei = ((size_t)(bs * 256 + o0) * 32 + p) * 256 + s0;
  #pragma unroll
  for (int q = 0; q < 16; ++q) {
    int c = grp * 16 + q;
    out[basei + (size_t)c * 8192 + lane] = tile[lane * 65 + c];
  }
}

// ---------------- launch ----------------
extern "C" void kernel_launch(void* const* d_in, const int* in_sizes, int n_in,
                              void* d_out, int out_size, void* d_ws, size_t ws_size,
                              hipStream_t stream) {
  (void)in_sizes; (void)n_in; (void)out_size; (void)ws_size;
  const float* x   = (const float*)d_in[0];
  const float* W1  = (const float*)d_in[1];
  const float* b1  = (const float*)d_in[2];
  const float* g1  = (const float*)d_in[3];
  const float* bt1 = (const float*)d_in[4];
  const float* W2  = (const float*)d_in[5];
  const float* b2  = (const float*)d_in[6];
  const float* g2  = (const float*)d_in[7];
  const float* bt2 = (const float*)d_in[8];
  const float* W3  = (const float*)d_in[9];
  const float* b3  = (const float*)d_in[10];
  const float* g3  = (const float*)d_in[11];
  const float* bt3 = (const float*)d_in[12];
  const float* W4  = (const float*)d_in[13];
  const float* b4  = (const float*)d_in[14];
  const float* g4  = (const float*)d_in[15];
  const float* bt4 = (const float*)d_in[16];
  const float* W5  = (const float*)d_in[17];
  const float* b5  = (const float*)d_in[18];
  const float* g5  = (const float*)d_in[19];
  const float* bt5 = (const float*)d_in[20];

  float* ws    = (float*)d_ws;
  float* hA    = ws + OFF_HA;
  float* hB    = ws + OFF_HB;
  float* UZ    = ws + OFF_UZ;
  float* ymx   = ws + OFF_YMAX;
  float* ymn   = ws + OFF_YMIN;
  int*   idxb  = (int*)(ws + OFF_IDX);
  float* Vt    = ws + OFF_VT;
  double* sums = (double*)(ws + OFF_SUMS);
  double* nd   = (double*)UZ;    // 64 MiB scratch, free during knn phase
  double* sqd  = (double*)ymx;   // 256 KiB scratch, free during knn phase

  prep_kernel<<<256, 256, 0, stream>>>(x, hA, W1, W2, W3, W4, W5, Vt, sums);

  // layer 1: hA (C=6) -> hB (O=16)
  sq_kernel<6><<<128, 256, 0, stream>>>(hA, sqd);
  dist_kernel<6><<<2048, 256, 0, stream>>>(hA, sqd, nd);
  topk_tourn_kernel<<<8192, 256, 0, stream>>>(nd, idxb);
  gemm_uz_kernel<6, 32><<<512, 256, 0, stream>>>(hA, Vt + 0, UZ);
  combine_kernel<16><<<256, 256, 0, stream>>>(UZ, idxb, b1, ymx, ymn, sums + 0);
  apply_kernel<16><<<2048, 256, 0, stream>>>(ymx, ymn, sums + 0, g1, bt1, hB);

  // layer 2: hB (C=16) -> hA (O=32)
  sq_kernel<16><<<128, 256, 0, stream>>>(hB, sqd);
  dist_kernel<16><<<2048, 256, 0, stream>>>(hB, sqd, nd);
  topk_tourn_kernel<<<8192, 256, 0, stream>>>(nd, idxb);
  gemm_uz_kernel<16, 64><<<512, 256, 0, stream>>>(hB, Vt + 192, UZ);
  combine_kernel<32><<<256, 256, 0, stream>>>(UZ, idxb, b2, ymx, ymn, sums + 32);
  apply_kernel<32><<<4096, 256, 0, stream>>>(ymx, ymn, sums + 32, g2, bt2, hA);

  // layer 3: hA (C=32) -> hB (O=64)
  sq_kernel<32><<<128, 256, 0, stream>>>(hA, sqd);
  dist_kernel<32><<<2048, 256, 0, stream>>>(hA, sqd, nd);
  topk_tourn_kernel<<<8192, 256, 0, stream>>>(nd, idxb);
  gemm_uz_kernel<32, 128><<<1024, 256, 0, stream>>>(hA, Vt + 1216, UZ);
  combine_kernel<64><<<256, 256, 0, stream>>>(UZ, idxb, b3, ymx, ymn, sums + 96);
  apply_kernel<64><<<8192, 256, 0, stream>>>(ymx, ymn, sums + 96, g3, bt3, hB);

  // layer 4: hB (C=64) -> hA (O=128)
  sq_kernel<64><<<128, 256, 0, stream>>>(hB, sqd);
  dist_kernel<64><<<2048, 256, 0, stream>>>(hB, sqd, nd);
  topk_tourn_kernel<<<8192, 256, 0, stream>>>(nd, idxb);
  gemm_uz_kernel<64, 256><<<2048, 256, 0, stream>>>(hB, Vt + 5312, UZ);
  combine_kernel<128><<<256, 256, 0, stream>>>(UZ, idxb, b4, ymx, ymn, sums + 224);
  apply_kernel<128><<<16384, 256, 0, stream>>>(ymx, ymn, sums + 224, g4, bt4, hA);

  // layer 5: hA (C=128) -> d_out (O=256, transposed layout)
  sq_kernel<128><<<128, 256, 0, stream>>>(hA, sqd);
  dist_kernel<128><<<2048, 256, 0, stream>>>(hA, sqd, nd);
  topk_tourn_kernel<<<8192, 256, 0, stream>>>(nd, idxb);
  gemm_uz_kernel<128, 512><<<4096, 256, 0, stream>>>(hA, Vt + 21696, UZ);
  combine_kernel<256><<<256, 256, 0, stream>>>(UZ, idxb, b5, ymx, ymn, sums + 480);
  apply_final_kernel<<<2048, 256, 0, stream>>>(ymx, ymn, sums + 480, g5, bt5, (float*)d_out);
}

// Round 10
// 884.970 us; speedup vs baseline: 1.4303x; 1.4303x over previous
//
#include <hip/hip_runtime.h>
#include <cmath>

#define NPTS 256
#define TOTPTS 32768
#define KNB 16

// ---------------- workspace layout (float-element offsets) ----------------
// UZ region doubles as the per-layer fp64 neg-dist matrix (64 MiB) during knn.
// YMAX region's head doubles as per-point fp64 sq norms (256 KiB) during knn.
static const size_t OFF_HA   = 0;
static const size_t OFF_HB   = 4194304;
static const size_t OFF_UZ   = 6291456;
static const size_t OFF_YMAX = 23068672;
static const size_t OFF_YMIN = 31457280;
static const size_t OFF_IDX  = 39845888;
static const size_t OFF_VT   = 40370176;
static const size_t OFF_SUMS = 40458240;   // byte offset 161,832,960 (8-aligned)

__device__ __forceinline__ float gelu_erf(float v) {
  return 0.5f * v * (1.0f + erff(v * 0.70710678118654752f));
}

// ---------------- prep: transpose x -> h0, build Vt, zero stats ----------------
__global__ __launch_bounds__(256) void prep_kernel(
    const float* __restrict__ x, float* __restrict__ h0,
    const float* __restrict__ W1, const float* __restrict__ W2, const float* __restrict__ W3,
    const float* __restrict__ W4, const float* __restrict__ W5,
    float* __restrict__ Vt, double* __restrict__ sums) {
  const int stride = gridDim.x * blockDim.x;
  const int tid0 = blockIdx.x * blockDim.x + threadIdx.x;
  // x: (4,6,32,256) -> h0: (128 clouds, 256 pts, 6 ch)
  for (int id = tid0; id < 196608; id += stride) {
    int ch = id % 6;
    int r  = id / 6;            // r = cloud*256 + s
    int s  = r & 255;
    int p  = (r >> 8) & 31;
    int bs = r >> 13;
    h0[id] = x[(((size_t)(bs * 6 + ch) * 32 + p) << 8) + s];
  }
  // Vt[l]: (Cin x 2O), Vt[c*2O + j] = W[j<O ? j*2Cin+c : (j-O)*2Cin+Cin+c]
  for (int id = tid0; id < 87232; id += stride) {
    const float* W; int K, N2, base;
    if (id < 192)        { W = W1; K = 6;   N2 = 32;  base = 0; }
    else if (id < 1216)  { W = W2; K = 16;  N2 = 64;  base = 192; }
    else if (id < 5312)  { W = W3; K = 32;  N2 = 128; base = 1216; }
    else if (id < 21696) { W = W4; K = 64;  N2 = 256; base = 5312; }
    else                 { W = W5; K = 128; N2 = 512; base = 21696; }
    int e = id - base;
    int c = e / N2;
    int j = e - c * N2;
    int O = N2 >> 1;
    Vt[id] = (j < O) ? W[j * 2 * K + c] : W[(j - O) * 2 * K + K + c];
  }
  for (int id = tid0; id < 992; id += stride) sums[id] = 0.0;
}

// ---------------- sq: per-point fp64 squared norm ----------------
template<int C>
__global__ __launch_bounds__(256) void sq_kernel(const float* __restrict__ h,
                                                 double* __restrict__ sqd) {
  const int n = blockIdx.x * 256 + threadIdx.x;
  const float* p = h + (size_t)n * C;
  double q0 = 0.0, q1 = 0.0;
  #pragma unroll
  for (int c = 0; c + 1 < C; c += 2) {
    q0 = fma((double)p[c],   (double)p[c],   q0);
    q1 = fma((double)p[c+1], (double)p[c+1], q1);
  }
  #pragma unroll
  for (int c = C & ~1; c < C; ++c) q0 = fma((double)p[c], (double)p[c], q0);
  sqd[n] = q0 + q1;
}

// ---------------- dist: fp64 neg-dist matrix, register-tiled GEMM ----------------
// nd[cloud][i][j] = 2*<h_i,h_j> - sq_i - sq_j  (exact ranking key, fp64)
// grid: 128 clouds x 16 tiles (4x4 grid of 64x64 tiles), 256 threads
template<int K>
__global__ __launch_bounds__(256) void dist_kernel(const float* __restrict__ h,
                                                   const double* __restrict__ sqd,
                                                   double* __restrict__ nd) {
  constexpr int KC = (K < 32) ? K : 32;
  __shared__ __align__(16) float As[KC * 68];   // [k][i]
  __shared__ __align__(16) float Bs[KC * 68];   // [k][j]
  const int cloud = blockIdx.x >> 4;
  const int tile  = blockIdx.x & 15;
  const int i0 = (tile >> 2) * 64;
  const int j0 = (tile & 3) * 64;
  const float* hb = h + (size_t)cloud * NPTS * K;
  const int tid = threadIdx.x;
  const int mm = (tid & 15) * 4;
  const int jj = (tid >> 4) * 4;
  double acc[4][4] = {{0.0}};
  for (int k0 = 0; k0 < K; k0 += KC) {
    for (int e = tid; e < 64 * KC; e += 256) {
      int am = e / KC, ac = e - am * KC;
      As[ac * 68 + am] = hb[(size_t)(i0 + am) * K + k0 + ac];
    }
    for (int e = tid; e < 64 * KC; e += 256) {
      int bm = e / KC, bc = e - bm * KC;
      Bs[bc * 68 + bm] = hb[(size_t)(j0 + bm) * K + k0 + bc];
    }
    __syncthreads();
    #pragma unroll
    for (int c = 0; c < KC; ++c) {
      float4 av = *(const float4*)(As + c * 68 + mm);
      float4 bv = *(const float4*)(Bs + c * 68 + jj);
      double a0 = (double)av.x, a1 = (double)av.y, a2 = (double)av.z, a3 = (double)av.w;
      double b0 = (double)bv.x, b1 = (double)bv.y, b2 = (double)bv.z, b3 = (double)bv.w;
      acc[0][0] = fma(a0, b0, acc[0][0]);
      acc[0][1] = fma(a0, b1, acc[0][1]);
      acc[0][2] = fma(a0, b2, acc[0][2]);
      acc[0][3] = fma(a0, b3, acc[0][3]);
      acc[1][0] = fma(a1, b0, acc[1][0]);
      acc[1][1] = fma(a1, b1, acc[1][1]);
      acc[1][2] = fma(a1, b2, acc[1][2]);
      acc[1][3] = fma(a1, b3, acc[1][3]);
      acc[2][0] = fma(a2, b0, acc[2][0]);
      acc[2][1] = fma(a2, b1, acc[2][1]);
      acc[2][2] = fma(a2, b2, acc[2][2]);
      acc[2][3] = fma(a2, b3, acc[2][3]);
      acc[3][0] = fma(a3, b0, acc[3][0]);
      acc[3][1] = fma(a3, b1, acc[3][1]);
      acc[3][2] = fma(a3, b2, acc[3][2]);
      acc[3][3] = fma(a3, b3, acc[3][3]);
    }
    __syncthreads();
  }
  double sqi[4], sqj[4];
  #pragma unroll
  for (int r = 0; r < 4; ++r) sqi[r] = sqd[cloud * NPTS + i0 + mm + r];
  #pragma unroll
  for (int s = 0; s < 4; ++s) sqj[s] = sqd[cloud * NPTS + j0 + jj + s];
  double* orow = nd + (size_t)cloud * NPTS * NPTS;
  #pragma unroll
  for (int r = 0; r < 4; ++r) {
    double v0 = 2.0 * acc[r][0] - sqi[r] - sqj[0];
    double v1 = 2.0 * acc[r][1] - sqi[r] - sqj[1];
    double v2 = 2.0 * acc[r][2] - sqi[r] - sqj[2];
    double v3 = 2.0 * acc[r][3] - sqi[r] - sqj[3];
    double* p = orow + (size_t)(i0 + mm + r) * NPTS + j0 + jj;
    *(double2*)(p)     = make_double2(v0, v1);
    *(double2*)(p + 2) = make_double2(v2, v3);
  }
}

// ------- topk: distributed merge of sorted register lists, u64 keys.
// Keys: nd values are <=0 (fp noise ~1e-13 near the diagonal), so
// value-DESCENDING order == ascending u64 bit order. Low 8 mantissa bits carry
// the column (perturbation ~2^-44 rel, selection-safe; exact-dup ties -> lower
// col). Only the index SET matters downstream (max/sum order-invariant).
// Mapping: each wave serves 4 rows = 2 chains x 2 half-wave rows. Lanes 0-31 own
// row A (chain1) + row C (chain2); lanes 32-63 own rows B + D. Each lane holds
// 8 keys (cols 8*sub..8*sub+7) per chain, SORTED ascending once via a static
// Batcher-8 network on named scalars (no arrays -> no scratch). Then 16 rounds:
// per chain a 5-step shfl_xor min butterfly (within halves) finds the winner;
// the owner lane shifts its sorted list down (local min is always a0/b0 — no
// recompute). Two independent chains interleave to hide shuffle latency.
__global__ __launch_bounds__(256) void topk_merge2_kernel(const double* __restrict__ nd,
                                                          int* __restrict__ idxout) {
  const unsigned long long FULL = 0xFFFFFFFFFFFFFFFFull;
  const int wid  = threadIdx.x >> 6;
  const int lane = threadIdx.x & 63;
  const int half = lane >> 5;
  const int sub  = lane & 31;
  const int rowAB = blockIdx.x * 16 + wid * 4 + half;
  const int rowCD = blockIdx.x * 16 + wid * 4 + 2 + half;
  const double* rp1 = nd + (size_t)rowAB * NPTS + 8 * sub;
  const double* rp2 = nd + (size_t)rowCD * NPTS + 8 * sub;
  const unsigned cb = 8u * (unsigned)sub;

  #define MK(P, Q) ((((unsigned long long)__double_as_longlong(P)) & ~0xFFull) | (cb + (Q)))
  double2 t0 = *(const double2*)(rp1);
  double2 t1 = *(const double2*)(rp1 + 2);
  double2 t2 = *(const double2*)(rp1 + 4);
  double2 t3 = *(const double2*)(rp1 + 6);
  unsigned long long a0 = MK(t0.x, 0u), a1 = MK(t0.y, 1u), a2 = MK(t1.x, 2u), a3 = MK(t1.y, 3u);
  unsigned long long a4 = MK(t2.x, 4u), a5 = MK(t2.y, 5u), a6 = MK(t3.x, 6u), a7 = MK(t3.y, 7u);
  t0 = *(const double2*)(rp2);
  t1 = *(const double2*)(rp2 + 2);
  t2 = *(const double2*)(rp2 + 4);
  t3 = *(const double2*)(rp2 + 6);
  unsigned long long b0 = MK(t0.x, 0u), b1 = MK(t0.y, 1u), b2 = MK(t1.x, 2u), b3 = MK(t1.y, 3u);
  unsigned long long b4 = MK(t2.x, 4u), b5 = MK(t2.y, 5u), b6 = MK(t3.x, 6u), b7 = MK(t3.y, 7u);
  #undef MK

  // Batcher odd-even sort-8, ascending (19 CE), on named scalars
  #define CE(X, Y) { unsigned long long lo_ = (X < Y) ? X : Y; \
                     unsigned long long hi_ = (X < Y) ? Y : X; X = lo_; Y = hi_; }
  #define SORT8(v0,v1,v2,v3,v4,v5,v6,v7) \
    CE(v0,v1) CE(v2,v3) CE(v4,v5) CE(v6,v7) \
    CE(v0,v2) CE(v1,v3) CE(v4,v6) CE(v5,v7) \
    CE(v1,v2) CE(v5,v6) \
    CE(v0,v4) CE(v1,v5) CE(v2,v6) CE(v3,v7) \
    CE(v2,v4) CE(v3,v5) \
    CE(v1,v2) CE(v3,v4) CE(v5,v6)
  SORT8(a0,a1,a2,a3,a4,a5,a6,a7)
  SORT8(b0,b1,b2,b3,b4,b5,b6,b7)
  #undef SORT8
  #undef CE

  int keep1 = 0, keep2 = 0;
  for (int round = 0; round < KNB; ++round) {
    unsigned long long m1 = a0, m2 = b0, o;
    o = __shfl_xor(m1, 16); m1 = (o < m1) ? o : m1;
    o = __shfl_xor(m2, 16); m2 = (o < m2) ? o : m2;
    o = __shfl_xor(m1, 8);  m1 = (o < m1) ? o : m1;
    o = __shfl_xor(m2, 8);  m2 = (o < m2) ? o : m2;
    o = __shfl_xor(m1, 4);  m1 = (o < m1) ? o : m1;
    o = __shfl_xor(m2, 4);  m2 = (o < m2) ? o : m2;
    o = __shfl_xor(m1, 2);  m1 = (o < m1) ? o : m1;
    o = __shfl_xor(m2, 2);  m2 = (o < m2) ? o : m2;
    o = __shfl_xor(m1, 1);  m1 = (o < m1) ? o : m1;
    o = __shfl_xor(m2, 1);  m2 = (o < m2) ? o : m2;
    const int col1 = (int)(m1 & 0xFFull);
    const int col2 = (int)(m2 & 0xFFull);
    if ((col1 >> 3) == sub) {  // owner of chain-1 winner: pop sorted list head
      a0 = a1; a1 = a2; a2 = a3; a3 = a4; a4 = a5; a5 = a6; a6 = a7; a7 = FULL;
    }
    if ((col2 >> 3) == sub) {
      b0 = b1; b1 = b2; b2 = b3; b3 = b4; b4 = b5; b5 = b6; b6 = b7; b7 = FULL;
    }
    if (sub == round) { keep1 = col1; keep2 = col2; }
  }
  if (sub < KNB) {
    idxout[(size_t)rowAB * KNB + sub] = (rowAB & ~(NPTS - 1)) + keep1;
    idxout[(size_t)rowCD * KNB + sub] = (rowCD & ~(NPTS - 1)) + keep2;
  }
}

// ---------------- GEMM: UZ(32768 x 2O) = h(32768 x K) * Vt(K x 2O) ----------------
template<int K, int N2>
__global__ __launch_bounds__(256) void gemm_uz_kernel(const float* __restrict__ h,
                                                      const float* __restrict__ Vt,
                                                      float* __restrict__ UZ) {
  constexpr int KC = 32;
  constexpr int NBLK = (N2 + 63) / 64;
  __shared__ __align__(16) float As[KC * 68];   // [k][m]
  __shared__ __align__(16) float Bs[KC * 68];   // [k][j]
  const int m0 = (int)(blockIdx.x / NBLK) * 64;
  const int n0 = (int)(blockIdx.x % NBLK) * 64;
  const int tid = threadIdx.x;
  const int mm = (tid & 15) * 4;
  const int jj = (tid >> 4) * 4;
  float acc[4][4] = {{0.f}};
  for (int k0 = 0; k0 < K; k0 += KC) {
    #pragma unroll
    for (int e = tid; e < 64 * KC; e += 256) {
      int am = e / KC, ac = e - am * KC;
      float v = 0.f;
      if (k0 + ac < K) v = h[(size_t)(m0 + am) * K + k0 + ac];
      As[ac * 68 + am] = v;
    }
    #pragma unroll
    for (int e = tid; e < KC * 64; e += 256) {
      int bj = e & 63, bc = e >> 6;
      float v = 0.f;
      if (k0 + bc < K && n0 + bj < N2) v = Vt[(size_t)(k0 + bc) * N2 + n0 + bj];
      Bs[bc * 68 + bj] = v;
    }
    __syncthreads();
    #pragma unroll
    for (int c = 0; c < KC; ++c) {
      float4 av = *(const float4*)(As + c * 68 + mm);
      float4 bv = *(const float4*)(Bs + c * 68 + jj);
      acc[0][0] = fmaf(av.x, bv.x, acc[0][0]);
      acc[0][1] = fmaf(av.x, bv.y, acc[0][1]);
      acc[0][2] = fmaf(av.x, bv.z, acc[0][2]);
      acc[0][3] = fmaf(av.x, bv.w, acc[0][3]);
      acc[1][0] = fmaf(av.y, bv.x, acc[1][0]);
      acc[1][1] = fmaf(av.y, bv.y, acc[1][1]);
      acc[1][2] = fmaf(av.y, bv.z, acc[1][2]);
      acc[1][3] = fmaf(av.y, bv.w, acc[1][3]);
      acc[2][0] = fmaf(av.z, bv.x, acc[2][0]);
      acc[2][1] = fmaf(av.z, bv.y, acc[2][1]);
      acc[2][2] = fmaf(av.z, bv.z, acc[2][2]);
      acc[2][3] = fmaf(av.z, bv.w, acc[2][3]);
      acc[3][0] = fmaf(av.w, bv.x, acc[3][0]);
      acc[3][1] = fmaf(av.w, bv.y, acc[3][1]);
      acc[3][2] = fmaf(av.w, bv.z, acc[3][2]);
      acc[3][3] = fmaf(av.w, bv.w, acc[3][3]);
    }
    __syncthreads();
  }
  if (n0 + jj < N2) {
    #pragma unroll
    for (int i = 0; i < 4; ++i) {
      float4 v = make_float4(acc[i][0], acc[i][1], acc[i][2], acc[i][3]);
      *(float4*)(UZ + (size_t)(m0 + mm + i) * N2 + n0 + jj) = v;
    }
  }
}

// ------- combine (x4 vectorized): gather u rows as float4, max/min + stats ------
template<int O>
__global__ __launch_bounds__(256) void combine_kernel(const float* __restrict__ UZ,
    const int* __restrict__ idx, const float* __restrict__ bias,
    float* __restrict__ ymax, float* __restrict__ ymin, double* __restrict__ sums) {
  constexpr int TPP = O / 4;            // threads per point
  constexpr int PPI = 256 / TPP;        // points per iteration
  constexpr int PPB = TOTPTS / 256;     // 128 points per block
  constexpr int ITERS = PPB / PPI;
  __shared__ double red[256];
  const int tid = threadIdx.x;
  const int oc  = tid % TPP;            // float4-channel index
  const int sub = tid / TPP;
  const int base = blockIdx.x * PPB;
  const float4* UZ4 = (const float4*)UZ;
  float4* ymx4 = (float4*)ymax;
  float4* ymn4 = (float4*)ymin;
  const float4 b4 = ((const float4*)bias)[oc];
  double a1x = 0.0, a1y = 0.0, a1z = 0.0, a1w = 0.0;
  double a2x = 0.0, a2y = 0.0, a2z = 0.0, a2w = 0.0;
  for (int it = 0; it < ITERS; ++it) {
    int n = base + it * PPI + sub;
    const int* ip = idx + (size_t)n * KNB;
    float4 un = UZ4[(size_t)n * (O / 2) + oc];
    float4 zn = UZ4[(size_t)n * (O / 2) + O / 4 + oc];
    float4 w = make_float4(zn.x - un.x + b4.x, zn.y - un.y + b4.y,
                           zn.z - un.z + b4.z, zn.w - un.w + b4.w);
    float4 mx = make_float4(-INFINITY, -INFINITY, -INFINITY, -INFINITY);
    float4 mn = make_float4(INFINITY, INFINITY, INFINITY, INFINITY);
    float4 s1 = make_float4(0.f, 0.f, 0.f, 0.f);
    float4 s2 = make_float4(0.f, 0.f, 0.f, 0.f);
    #pragma unroll
    for (int kk = 0; kk < KNB; ++kk) {
      int j = ip[kk];
      float4 uv = UZ4[(size_t)j * (O / 2) + oc];
      mx.x = fmaxf(mx.x, uv.x); mx.y = fmaxf(mx.y, uv.y);
      mx.z = fmaxf(mx.z, uv.z); mx.w = fmaxf(mx.w, uv.w);
      mn.x = fminf(mn.x, uv.x); mn.y = fminf(mn.y, uv.y);
      mn.z = fminf(mn.z, uv.z); mn.w = fminf(mn.w, uv.w);
      s1.x += uv.x; s1.y += uv.y; s1.z += uv.z; s1.w += uv.w;
      s2.x = fmaf(uv.x, uv.x, s2.x); s2.y = fmaf(uv.y, uv.y, s2.y);
      s2.z = fmaf(uv.z, uv.z, s2.z); s2.w = fmaf(uv.w, uv.w, s2.w);
    }
    ymx4[(size_t)n * (O / 4) + oc] = make_float4(mx.x + w.x, mx.y + w.y, mx.z + w.z, mx.w + w.w);
    ymn4[(size_t)n * (O / 4) + oc] = make_float4(mn.x + w.x, mn.y + w.y, mn.z + w.z, mn.w + w.w);
    a1x += (double)(s1.x + 16.f * w.x);
    a1y += (double)(s1.y + 16.f * w.y);
    a1z += (double)(s1.z + 16.f * w.z);
    a1w += (double)(s1.w + 16.f * w.w);
    a2x += (double)(s2.x + 2.f * w.x * s1.x + 16.f * (w.x * w.x));
    a2y += (double)(s2.y + 2.f * w.y * s1.y + 16.f * (w.y * w.y));
    a2z += (double)(s2.z + 2.f * w.z * s1.z + 16.f * (w.z * w.z));
    a2w += (double)(s2.w + 2.f * w.w * s1.w + 16.f * (w.w * w.w));
  }
  #define REDUCE_ONE(VAL, CH_OFF)                                        \
    red[tid] = (VAL);                                                    \
    __syncthreads();                                                     \
    if (tid < TPP) {                                                     \
      double t = 0.0;                                                    \
      _Pragma("unroll")                                                  \
      for (int q = 0; q < PPI; ++q) t += red[q * TPP + tid];             \
      atomicAdd(&sums[(CH_OFF) + 4 * tid], t);                           \
    }                                                                    \
    __syncthreads();
  REDUCE_ONE(a1x, 0)
  REDUCE_ONE(a1y, 1)
  REDUCE_ONE(a1z, 2)
  REDUCE_ONE(a1w, 3)
  REDUCE_ONE(a2x, O + 0)
  REDUCE_ONE(a2y, O + 1)
  REDUCE_ONE(a2z, O + 2)
  REDUCE_ONE(a2w, O + 3)
  #undef REDUCE_ONE
}

// ---------------- apply: BN affine + erf-GELU + endpoint max ----------------
template<int O>
__global__ __launch_bounds__(256) void apply_kernel(const float* __restrict__ ymax,
    const float* __restrict__ ymin, const double* __restrict__ sums,
    const float* __restrict__ g, const float* __restrict__ bt, float* __restrict__ hout) {
  const int tid = blockIdx.x * 256 + threadIdx.x;
  const int o = tid & (O - 1);
  double m = sums[o] * (1.0 / 524288.0);
  double v = fma(-m, m, sums[O + o] * (1.0 / 524288.0));
  float A = g[o] / sqrtf((float)v + 1e-5f);
  float Cc = fmaf(-(float)m, A, bt[o]);
  float r1 = gelu_erf(fmaf(A, ymax[tid], Cc));
  float r2 = gelu_erf(fmaf(A, ymin[tid], Cc));
  hout[tid] = fmaxf(r1, r2);
}

// layer-5 apply, transposes (n,o) -> (bs, o, p, s) via LDS tile
__global__ __launch_bounds__(256) void apply_final_kernel(const float* __restrict__ ymax,
    const float* __restrict__ ymin, const double* __restrict__ sums,
    const float* __restrict__ g, const float* __restrict__ bt, float* __restrict__ out) {
  constexpr int O = 256;
  __shared__ float tile[64 * 65];
  const int bo = blockIdx.x & 3;
  const int bn = blockIdx.x >> 2;
  const int n0 = bn * 64, o0 = bo * 64;
  const int lane = threadIdx.x & 63;
  const int grp = threadIdx.x >> 6;
  {
    const int oc = o0 + lane;
    double m = sums[oc] * (1.0 / 524288.0);
    double v = fma(-m, m, sums[O + oc] * (1.0 / 524288.0));
    float A = g[oc] / sqrtf((float)v + 1e-5f);
    float Cc = fmaf(-(float)m, A, bt[oc]);
    #pragma unroll
    for (int q = 0; q < 16; ++q) {
      int r = grp * 16 + q;
      size_t src = (size_t)(n0 + r) * O + oc;
      float r1 = gelu_erf(fmaf(A, ymax[src], Cc));
      float r2 = gelu_erf(fmaf(A, ymin[src], Cc));
      tile[r * 65 + lane] = fmaxf(r1, r2);
    }
  }
  __syncthreads();
  const int s0 = n0 & 255;
  const int p  = (n0 >> 8) & 31;
  const int bs = n0 >> 13;
  size_t basei = ((size_t)(bs * 256 + o0) * 32 + p) * 256 + s0;
  #pragma unroll
  for (int q = 0; q < 16; ++q) {
    int c = grp * 16 + q;
    out[basei + (size_t)c * 8192 + lane] = tile[lane * 65 + c];
  }
}

// ---------------- launch ----------------
extern "C" void kernel_launch(void* const* d_in, const int* in_sizes, int n_in,
                              void* d_out, int out_size, void* d_ws, size_t ws_size,
                              hipStream_t stream) {
  (void)in_sizes; (void)n_in; (void)out_size; (void)ws_size;
  const float* x   = (const float*)d_in[0];
  const float* W1  = (const float*)d_in[1];
  const float* b1  = (const float*)d_in[2];
  const float* g1  = (const float*)d_in[3];
  const float* bt1 = (const float*)d_in[4];
  const float* W2  = (const float*)d_in[5];
  const float* b2  = (const float*)d_in[6];
  const float* g2  = (const float*)d_in[7];
  const float* bt2 = (const float*)d_in[8];
  const float* W3  = (const float*)d_in[9];
  const float* b3  = (const float*)d_in[10];
  const float* g3  = (const float*)d_in[11];
  const float* bt3 = (const float*)d_in[12];
  const float* W4  = (const float*)d_in[13];
  const float* b4  = (const float*)d_in[14];
  const float* g4  = (const float*)d_in[15];
  const float* bt4 = (const float*)d_in[16];
  const float* W5  = (const float*)d_in[17];
  const float* b5  = (const float*)d_in[18];
  const float* g5  = (const float*)d_in[19];
  const float* bt5 = (const float*)d_in[20];

  float* ws    = (float*)d_ws;
  float* hA    = ws + OFF_HA;
  float* hB    = ws + OFF_HB;
  float* UZ    = ws + OFF_UZ;
  float* ymx   = ws + OFF_YMAX;
  float* ymn   = ws + OFF_YMIN;
  int*   idxb  = (int*)(ws + OFF_IDX);
  float* Vt    = ws + OFF_VT;
  double* sums = (double*)(ws + OFF_SUMS);
  double* nd   = (double*)UZ;    // 64 MiB scratch, free during knn phase
  double* sqd  = (double*)ymx;   // 256 KiB scratch, free during knn phase

  prep_kernel<<<256, 256, 0, stream>>>(x, hA, W1, W2, W3, W4, W5, Vt, sums);

  // layer 1: hA (C=6) -> hB (O=16)
  sq_kernel<6><<<128, 256, 0, stream>>>(hA, sqd);
  dist_kernel<6><<<2048, 256, 0, stream>>>(hA, sqd, nd);
  topk_merge2_kernel<<<2048, 256, 0, stream>>>(nd, idxb);
  gemm_uz_kernel<6, 32><<<512, 256, 0, stream>>>(hA, Vt + 0, UZ);
  combine_kernel<16><<<256, 256, 0, stream>>>(UZ, idxb, b1, ymx, ymn, sums + 0);
  apply_kernel<16><<<2048, 256, 0, stream>>>(ymx, ymn, sums + 0, g1, bt1, hB);

  // layer 2: hB (C=16) -> hA (O=32)
  sq_kernel<16><<<128, 256, 0, stream>>>(hB, sqd);
  dist_kernel<16><<<2048, 256, 0, stream>>>(hB, sqd, nd);
  topk_merge2_kernel<<<2048, 256, 0, stream>>>(nd, idxb);
  gemm_uz_kernel<16, 64><<<512, 256, 0, stream>>>(hB, Vt + 192, UZ);
  combine_kernel<32><<<256, 256, 0, stream>>>(UZ, idxb, b2, ymx, ymn, sums + 32);
  apply_kernel<32><<<4096, 256, 0, stream>>>(ymx, ymn, sums + 32, g2, bt2, hA);

  // layer 3: hA (C=32) -> hB (O=64)
  sq_kernel<32><<<128, 256, 0, stream>>>(hA, sqd);
  dist_kernel<32><<<2048, 256, 0, stream>>>(hA, sqd, nd);
  topk_merge2_kernel<<<2048, 256, 0, stream>>>(nd, idxb);
  gemm_uz_kernel<32, 128><<<1024, 256, 0, stream>>>(hA, Vt + 1216, UZ);
  combine_kernel<64><<<256, 256, 0, stream>>>(UZ, idxb, b3, ymx, ymn, sums + 96);
  apply_kernel<64><<<8192, 256, 0, stream>>>(ymx, ymn, sums + 96, g3, bt3, hB);

  // layer 4: hB (C=64) -> hA (O=128)
  sq_kernel<64><<<128, 256, 0, stream>>>(hB, sqd);
  dist_kernel<64><<<2048, 256, 0, stream>>>(hB, sqd, nd);
  topk_merge2_kernel<<<2048, 256, 0, stream>>>(nd, idxb);
  gemm_uz_kernel<64, 256><<<2048, 256, 0, stream>>>(hB, Vt + 5312, UZ);
  combine_kernel<128><<<256, 256, 0, stream>>>(UZ, idxb, b4, ymx, ymn, sums + 224);
  apply_kernel<128><<<16384, 256, 0, stream>>>(ymx, ymn, sums + 224, g4, bt4, hA);

  // layer 5: hA (C=128) -> d_out (O=256, transposed layout)
  sq_kernel<128><<<128, 256, 0, stream>>>(hA, sqd);
  dist_kernel<128><<<2048, 256, 0, stream>>>(hA, sqd, nd);
  topk_merge2_kernel<<<2048, 256, 0, stream>>>(nd, idxb);
  gemm_uz_kernel<128, 512><<<4096, 256, 0, stream>>>(hA, Vt + 21696, UZ);
  combine_kernel<256><<<256, 256, 0, stream>>>(UZ, idxb, b5, ymx, ymn, sums + 480);
  apply_final_kernel<<<2048, 256, 0, stream>>>(ymx, ymn, sums + 480, g5, bt5, (float*)d_out);
}